// Round 5
// baseline (239.000 us; speedup 1.0000x reference)
//
#include <hip/hip_runtime.h>

// 3D spatial transformer (trilinear warp), voxelmorph semantics.
// vol: [B=2, X=160, Y=192, Z=160, C=1] fp32
// trf: [B=2, X=160, Y=192, Z=160, 3]  fp32 (dense displacement)
// out: same shape as vol, fp32.
//
// R9: persistent z-column blocks + double-buffered slab pipeline.
// Evidence: R4-R8 pinned at 78-81us with every pipe idle (HBM 20%, VALU 29%,
// LDS ~15%, occ 53%) while conflicts/FETCH/LDS-size all varied -> the cost is
// the per-block convoy (launch -> stage -> EXPOSED vmcnt(0) drain -> compute)
// x 4800 short blocks. Fix: 480 blocks, one per (b,tx,ty) column; each sweeps
// tz=0..9; slab k+1 staging + trf prefetch issue BEFORE slab k compute, so
// the per-slab barrier drain lands after ~2000cy of compute (hidden).
// Compute mapping / 16B-swizzle / halo-3 window / fallback identical to R8.
// LDS = 2 x 38.5 KB = 77 KB -> 2 blocks/CU (16 waves). Staging offsets are
// slab-invariant -> precomputed once (o0..o4, named regs, no arrays).

#define NXD 160
#define NYD 192
#define NZD 160
#define NVOX (NXD * NYD * NZD)
#define NBATCH 2

#define TXT 8
#define TYT 16
#define TZT 16
#define NZT (NZD / TZT)   // 10 slabs per column
#define LXT 14            // staged x extent (halo 3)
#define LYT 22            // staged y extent (halo 3)
#define LZT 32            // staged z extent (halo 8)
#define NROWS (LXT * LYT)          // 308 z-rows
#define LDS_N (NROWS * LZT)        // 9856 floats = 38.5 KB per buffer
#define NSLOT (NROWS * 8)          // 2464 16B staging slots

#define TILES_X (NXD / TXT)   // 20
#define TILES_Y (NYD / TYT)   // 12
#define NBLOCKS (NBATCH * TILES_X * TILES_Y)   // 480 column-blocks

typedef float f4 __attribute__((ext_vector_type(4)));

#define AS1 __attribute__((address_space(1)))
#define AS3 __attribute__((address_space(3)))

__global__ __launch_bounds__(512)
void warp3d_kernel(const float* __restrict__ vol,
                   const float* __restrict__ trf,
                   float* __restrict__ out) {
    __shared__ float tile[2 * LDS_N];   // 77 KB double buffer

    // chunked XCD swizzle (480 % 8 == 0, bijective): y-adjacent columns
    // land on the same XCD -> halo/trf L2 reuse.
    int bid0 = blockIdx.x;
    int bid = (bid0 & 7) * (NBLOCKS / 8) + (bid0 >> 3);

    int ty = bid % TILES_Y;
    int r  = bid / TILES_Y;
    int tx = r % TILES_X;
    int b  = r / TILES_X;

    int x0t = tx * TXT, y0t = ty * TYT;
    int lox = min(max(x0t - 3, 0), NXD - LXT);
    int loy = min(max(y0t - 3, 0), NYD - LYT);

    const float* vb = vol + (size_t)b * NVOX;

    int t = threadIdx.x;
    // compute-phase voxel quad: 4 z-consecutive voxels per thread (f4 I/O)
    int zq = t & 3;             // 4 z-quads
    int yq = (t >> 2) & 15;     // 16 y
    int xq = t >> 6;            // 8 x (== wave id)
    int x = x0t + xq, y = y0t + yq;
    size_t rowb = (((size_t)b * NXD + x) * NYD + y) * NZD + zq * 4;

    // ---- precompute slab-invariant staging offsets (5 slots/thread) ----
    int o0, o1, o2, o3, o4;
    {
#define MKOFF(IT, DST)                                                    \
        {                                                                  \
            int slot = (IT) * 512 + t;                                     \
            int row = slot >> 3;                                           \
            int zg  = (slot & 7) << 2;                                     \
            int yi  = row % LYT;                                           \
            int xi  = row / LYT;                                           \
            int sz  = zg ^ ((yi & 7) << 2);  /* involution, 16B-preserving */ \
            DST = xi * (NYD * NZD) + yi * NZD + sz;                        \
        }
        MKOFF(0, o0) MKOFF(1, o1) MKOFF(2, o2) MKOFF(3, o3) MKOFF(4, o4)
#undef MKOFF
    }
    bool p4 = (2048 + t) < NSLOT;   // last staging wave-round is partial

    // stage one slab's window into tile[bufoff..] (dest linear in slot;
    // source z inverse-swizzled; 16B async loads)
    auto STAGE = [&](int bufoff, int loz) {
        const float* gb = vb + ((size_t)(lox * NYD + loy) * NZD + loz);
        __builtin_amdgcn_global_load_lds((const AS1 void*)(gb + o0),
            (AS3 void*)&tile[bufoff + t * 4], 16, 0, 0);
        __builtin_amdgcn_global_load_lds((const AS1 void*)(gb + o1),
            (AS3 void*)&tile[bufoff + (512 + t) * 4], 16, 0, 0);
        __builtin_amdgcn_global_load_lds((const AS1 void*)(gb + o2),
            (AS3 void*)&tile[bufoff + (1024 + t) * 4], 16, 0, 0);
        __builtin_amdgcn_global_load_lds((const AS1 void*)(gb + o3),
            (AS3 void*)&tile[bufoff + (1536 + t) * 4], 16, 0, 0);
        if (p4)
            __builtin_amdgcn_global_load_lds((const AS1 void*)(gb + o4),
                (AS3 void*)&tile[bufoff + (2048 + t) * 4], 16, 0, 0);
    };

    // ---- prologue: slab 0 ----
    int bufoff = 0;
    int loz = 0;   // clamp(0*16-8, 0, 128) == 0
    f4 ta0, ta1, ta2;
    {
        const f4* tv = (const f4*)(trf + rowb * 3);
        ta0 = tv[0]; ta1 = tv[1]; ta2 = tv[2];
    }
    STAGE(0, 0);
    __syncthreads();   // only exposed drain of the column

    // ---- slab loop: issue next staging + trf, then compute current ----
    for (int tz = 0; tz < NZT; ++tz) {
        bool pre = (tz + 1) < NZT;
        int loz_next = min(max((tz + 1) * TZT - 8, 0), NZD - LZT);
        f4 tb0, tb1, tb2;
        if (pre) {
            const f4* tv = (const f4*)(trf + (rowb + (size_t)(tz + 1) * TZT) * 3);
            tb0 = tv[0]; tb1 = tv[1]; tb2 = tv[2];
            STAGE(bufoff ^ LDS_N, loz_next);
        }

        // ---- compute slab tz from tile[bufoff..] ----
        int zb0 = tz * TZT + zq * 4;
        float dxa[4] = {ta0.x, ta0.w, ta1.z, ta2.y};
        float dya[4] = {ta0.y, ta1.x, ta1.w, ta2.z};
        float dza[4] = {ta0.z, ta1.y, ta2.x, ta2.w};

        float res[4];
#pragma unroll
        for (int j = 0; j < 4; ++j) {
            float lx = fminf(fmaxf((float)x + dxa[j], 0.0f), (float)(NXD - 1));
            float ly = fminf(fmaxf((float)y + dya[j], 0.0f), (float)(NYD - 1));
            float lz = fminf(fmaxf((float)(zb0 + j) + dza[j], 0.0f), (float)(NZD - 1));
            float fx = floorf(lx), fy = floorf(ly), fz = floorf(lz);
            int x0 = (int)fx, y0 = (int)fy, z0 = (int)fz;
            // lower-corner weights d1 = loc1 - loc (0 at clamped top border)
            float wx0 = fminf(fx + 1.0f, (float)(NXD - 1)) - lx;
            float wy0 = fminf(fy + 1.0f, (float)(NYD - 1)) - ly;
            float wz0 = fminf(fz + 1.0f, (float)(NZD - 1)) - lz;

            int ix = x0 - lox, iy = y0 - loy, iz = z0 - loz;
            bool ok = ((unsigned)ix <= LXT - 2) & ((unsigned)iy <= LYT - 2) &
                      ((unsigned)iz <= LZT - 2);
            int sx = ok ? ix : 0;            // safe LDS coords when !ok
            int sy = ok ? iy : 0;
            int sv = ok ? iz : 0;

            int base = bufoff + (sx * LYT + sy) * LZT;
            int sw0 = (sy & 7) << 2;
            int sw1 = ((sy + 1) & 7) << 2;
            int A = base + (sv ^ sw0);                    // (y0, z0)
            int B = base + ((sv + 1) ^ sw0);              // (y0, z1)
            int C = base + LZT + (sv ^ sw1);              // (y1, z0)
            int D = base + LZT + ((sv + 1) ^ sw1);        // (y1, z1)

            float v000 = tile[A],              v001 = tile[B];
            float v010 = tile[C],              v011 = tile[D];
            float v100 = tile[A + LYT * LZT],  v101 = tile[B + LYT * LZT];
            float v110 = tile[C + LYT * LZT],  v111 = tile[D + LYT * LZT];

            if (!ok) {   // rare: sample outside staged window -> global
                int x1 = min(x0 + 1, NXD - 1);
                int y1 = min(y0 + 1, NYD - 1);
                int z1 = min(z0 + 1, NZD - 1);
                size_t o00 = (size_t)(x0 * NYD + y0) * NZD;
                size_t o01 = (size_t)(x0 * NYD + y1) * NZD;
                size_t o10 = (size_t)(x1 * NYD + y0) * NZD;
                size_t o11 = (size_t)(x1 * NYD + y1) * NZD;
                v000 = vb[o00 + z0]; v001 = vb[o00 + z1];
                v010 = vb[o01 + z0]; v011 = vb[o01 + z1];
                v100 = vb[o10 + z0]; v101 = vb[o10 + z1];
                v110 = vb[o11 + z0]; v111 = vb[o11 + z1];
            }

            float wx1 = 1.0f - wx0, wy1 = 1.0f - wy0, wz1 = 1.0f - wz0;
            res[j] = wx0 * (wy0 * (wz0 * v000 + wz1 * v001) +
                            wy1 * (wz0 * v010 + wz1 * v011)) +
                     wx1 * (wy0 * (wz0 * v100 + wz1 * v101) +
                            wy1 * (wz0 * v110 + wz1 * v111));
        }

        f4 o;
        o.x = res[0]; o.y = res[1]; o.z = res[2]; o.w = res[3];
        *(f4*)(out + rowb + (size_t)tz * TZT) = o;

        __syncthreads();   // drains next-slab staging (after compute) + syncs
        if (pre) {
            ta0 = tb0; ta1 = tb1; ta2 = tb2;
            bufoff ^= LDS_N;
            loz = loz_next;
        }
    }
}

extern "C" void kernel_launch(void* const* d_in, const int* in_sizes, int n_in,
                              void* d_out, int out_size, void* d_ws, size_t ws_size,
                              hipStream_t stream) {
    const float* vol = (const float*)d_in[0];
    const float* trf = (const float*)d_in[1];
    float* out = (float*)d_out;

    warp3d_kernel<<<NBLOCKS, 512, 0, stream>>>(vol, trf, out);
}